// Round 11
// baseline (177.909 us; speedup 1.0000x reference)
//
#include <hip/hip_runtime.h>
#include <math.h>

// Burgers PINN: u = MLP(x,t) (2->10x7->1, tanh), outputs u, f, u_x, u_xx at 1M
// collocation points + plain forward at 3x16384 IC/boundary points.
// Forward-mode AD with 4 channels: (val, d/dx, d/dt, d2/dx2).
//
// R11: WEIGHTS IN LDS. R5-R10 invariant: VALUBusy caps at ~76-79% at any
// occupancy/VGPR config -> phase-correlated stall = per-layer weight s_load
// bubbles (110 floats/layer > ~96 usable SGPRs: no cross-layer prefetch
// possible). Staging all 811 weights to LDS once/block turns layer reads
// into ds_read_b64 broadcasts landing in VGPRs (256-reg budget) -> scheduler
// can prefetch next layer's weights under current layer's compute.
// Body = R10 (2 points/thread, packed fp32), only the weight source changed.

#define NU_CONST 0.0031830988618379067f   // 0.01 / pi
#define TWO_OVER_LN2 2.8853900817779268f  // 2 / ln(2)

typedef float v2f __attribute__((ext_vector_type(2)));

__device__ __forceinline__ v2f splat2(float s) {
    v2f r; r.x = s; r.y = s; return r;
}
__device__ __forceinline__ v2f pk_fma(v2f a, v2f b, v2f c) {
    return __builtin_elementwise_fma(a, b, c);
}

__device__ __forceinline__ float fast_tanh(float x) {
    float e = __builtin_amdgcn_exp2f(x * TWO_OVER_LN2);
    float r = __builtin_amdgcn_rcpf(e + 1.0f);
    return fmaf(-2.0f, r, 1.0f);
}

// Packed tanh on a pair.
__device__ __forceinline__ v2f tanh2(v2f z2) {
    v2f a2 = z2 * splat2(TWO_OVER_LN2);
    v2f e2;
    e2.x = __builtin_amdgcn_exp2f(a2.x);
    e2.y = __builtin_amdgcn_exp2f(a2.y);
    v2f ep = e2 + splat2(1.0f);
    v2f r2;
    r2.x = __builtin_amdgcn_rcpf(ep.x);
    r2.y = __builtin_amdgcn_rcpf(ep.y);
    return pk_fma(splat2(-2.0f), r2, splat2(1.0f));
}

// LDS weight layout (floats, all pair-offsets even => 8B-aligned ds_read_b64):
//   W1: [0,20)   b1: [20,30)
//   Wk (k=2..8): [30+(k-2)*110, +100)   bk: [130+(k-2)*110, +10)
//   W9: [800,810)   b9: [810]
#define LDS_W1  0
#define LDS_B1  20
#define LDS_WK(k) (30 + ((k) - 2) * 110)
#define LDS_BK(k) (130 + ((k) - 2) * 110)
#define LDS_W9  800
#define LDS_B9  810

// One hidden 10->10 tanh layer, 4 AD channels, TWO points per thread.
// W,B point into LDS; each ds_read_b64 pair feeds 8 pk_fmas.
__device__ __forceinline__ void hidden10_ad_x2(const float* W, const float* B,
                                               float h[2][10], float hx[2][10],
                                               float ht[2][10], float hxx[2][10]) {
    v2f Z[2][5], Zx[2][5], Zt[2][5], Zxx[2][5];
#pragma unroll
    for (int jp = 0; jp < 5; ++jp) {
        v2f w2 = *(const v2f*)(W + 2 * jp);   // LDS broadcast
        v2f b2 = *(const v2f*)(B + 2 * jp);
#pragma unroll
        for (int p = 0; p < 2; ++p) {
            Z[p][jp]   = pk_fma(splat2(h[p][0]), w2, b2);
            Zx[p][jp]  = splat2(hx[p][0]) * w2;
            Zt[p][jp]  = splat2(ht[p][0]) * w2;
            Zxx[p][jp] = splat2(hxx[p][0]) * w2;
        }
    }
#pragma unroll
    for (int i = 1; i < 10; ++i) {
#pragma unroll
        for (int jp = 0; jp < 5; ++jp) {
            v2f w2 = *(const v2f*)(W + i * 10 + 2 * jp);
#pragma unroll
            for (int p = 0; p < 2; ++p) {
                Z[p][jp]   = pk_fma(splat2(h[p][i]),   w2, Z[p][jp]);
                Zx[p][jp]  = pk_fma(splat2(hx[p][i]),  w2, Zx[p][jp]);
                Zt[p][jp]  = pk_fma(splat2(ht[p][i]),  w2, Zt[p][jp]);
                Zxx[p][jp] = pk_fma(splat2(hxx[p][i]), w2, Zxx[p][jp]);
            }
        }
    }
#pragma unroll
    for (int p = 0; p < 2; ++p) {
#pragma unroll
        for (int jp = 0; jp < 5; ++jp) {
            v2f v2v = tanh2(Z[p][jp]);
            v2f s2  = pk_fma(-v2v, v2v, splat2(1.0f));   // 1 - v^2
            v2f sx2 = s2 * Zx[p][jp];
            v2f m2v = splat2(-2.0f) * v2v;
            v2f htn2 = s2 * Zt[p][jp];
            // d2/dx2 tanh(z) = s*zxx + (-2v)*(sx*zx)
            v2f hxxn2 = pk_fma(s2, Zxx[p][jp], m2v * (sx2 * Zx[p][jp]));
            h[p][2*jp]   = v2v.x;   h[p][2*jp+1]   = v2v.y;
            hx[p][2*jp]  = sx2.x;   hx[p][2*jp+1]  = sx2.y;
            ht[p][2*jp]  = htn2.x;  ht[p][2*jp+1]  = htn2.y;
            hxx[p][2*jp] = hxxn2.x; hxx[p][2*jp+1] = hxxn2.y;
        }
    }
}

// Values-only hidden layer (boundary/IC points), weights from LDS.
__device__ __forceinline__ void hidden10_fwd(const float* W, const float* B,
                                             float h[10]) {
    v2f Z[5];
    {
        v2f hs = splat2(h[0]);
#pragma unroll
        for (int jp = 0; jp < 5; ++jp) {
            v2f w2 = *(const v2f*)(W + 2 * jp);
            v2f b2 = *(const v2f*)(B + 2 * jp);
            Z[jp] = pk_fma(hs, w2, b2);
        }
    }
#pragma unroll
    for (int i = 1; i < 10; ++i) {
        v2f hs = splat2(h[i]);
#pragma unroll
        for (int jp = 0; jp < 5; ++jp) {
            v2f w2 = *(const v2f*)(W + i * 10 + 2 * jp);
            Z[jp] = pk_fma(hs, w2, Z[jp]);
        }
    }
#pragma unroll
    for (int jp = 0; jp < 5; ++jp) {
        v2f v2v = tanh2(Z[jp]);
        h[2*jp] = v2v.x;
        h[2*jp+1] = v2v.y;
    }
}

__global__ __launch_bounds__(256)
__attribute__((amdgpu_waves_per_eu(2, 2)))
void pinn_fused_kernel(
    const float* __restrict__ Xf,
    const float* __restrict__ X0, const float* __restrict__ XL,
    const float* __restrict__ XR,
    const float* __restrict__ W1, const float* __restrict__ b1,
    const float* __restrict__ W2, const float* __restrict__ b2,
    const float* __restrict__ W3, const float* __restrict__ b3,
    const float* __restrict__ W4, const float* __restrict__ b4,
    const float* __restrict__ W5, const float* __restrict__ b5,
    const float* __restrict__ W6, const float* __restrict__ b6,
    const float* __restrict__ W7, const float* __restrict__ b7,
    const float* __restrict__ W8, const float* __restrict__ b8,
    const float* __restrict__ W9, const float* __restrict__ b9,
    float* __restrict__ out_u, float* __restrict__ out_f,
    float* __restrict__ out_ux, float* __restrict__ out_uxx,
    float* __restrict__ O0, float* __restrict__ OL, float* __restrict__ OR_,
    int n_colloc_blocks, int NF2, int N0) {
    __shared__ __align__(16) float wl[812];
    {
        int tid = threadIdx.x;
        if (tid < 20) wl[LDS_W1 + tid] = W1[tid];
        if (tid < 10) wl[LDS_B1 + tid] = b1[tid];
        const float* Ws[7] = {W2, W3, W4, W5, W6, W7, W8};
        const float* Bs[7] = {b2, b3, b4, b5, b6, b7, b8};
#pragma unroll
        for (int k = 0; k < 7; ++k) {
            if (tid < 100) wl[LDS_WK(k + 2) + tid] = Ws[k][tid];
            if (tid < 10)  wl[LDS_BK(k + 2) + tid] = Bs[k][tid];
        }
        if (tid < 10)  wl[LDS_W9 + tid] = W9[tid];
        if (tid == 0)  wl[LDS_B9] = b9[0];
    }
    __syncthreads();

    if ((int)blockIdx.x < n_colloc_blocks) {
        // ------------- collocation path: 2 points, 4 AD channels -------------
        int gid = blockIdx.x * blockDim.x + threadIdx.x;   // pair index
        if (gid >= NF2) return;
        float4 xt2 = ((const float4*)Xf)[gid];   // (x0,t0,x1,t1)
        float xin[2], tin[2];
        xin[0] = xt2.x; tin[0] = xt2.y;
        xin[1] = xt2.z; tin[1] = xt2.w;

        float h[2][10], hx[2][10], ht[2][10], hxx[2][10];
        // Layer 1: 2 -> 10, tanh. Seeds: dx=(1,0), dt=(0,1), dxx=0.
#pragma unroll
        for (int jp = 0; jp < 5; ++jp) {
            v2f wx2 = *(const v2f*)(wl + LDS_W1 + 2 * jp);        // row 0
            v2f wt2 = *(const v2f*)(wl + LDS_W1 + 10 + 2 * jp);   // row 1
            v2f b2  = *(const v2f*)(wl + LDS_B1 + 2 * jp);
#pragma unroll
            for (int p = 0; p < 2; ++p) {
                v2f z2  = pk_fma(splat2(xin[p]), wx2,
                                 pk_fma(splat2(tin[p]), wt2, b2));
                v2f v2v = tanh2(z2);
                v2f s2  = pk_fma(-v2v, v2v, splat2(1.0f));
                v2f sx2 = s2 * wx2;
                v2f m2v = splat2(-2.0f) * v2v;
                v2f st2 = s2 * wt2;
                v2f sxx2 = m2v * (sx2 * wx2);   // zxx = 0 at layer 1
                h[p][2*jp]   = v2v.x;  h[p][2*jp+1]   = v2v.y;
                hx[p][2*jp]  = sx2.x;  hx[p][2*jp+1]  = sx2.y;
                ht[p][2*jp]  = st2.x;  ht[p][2*jp+1]  = st2.y;
                hxx[p][2*jp] = sxx2.x; hxx[p][2*jp+1] = sxx2.y;
            }
        }

        hidden10_ad_x2(wl + LDS_WK(2), wl + LDS_BK(2), h, hx, ht, hxx);
        hidden10_ad_x2(wl + LDS_WK(3), wl + LDS_BK(3), h, hx, ht, hxx);
        hidden10_ad_x2(wl + LDS_WK(4), wl + LDS_BK(4), h, hx, ht, hxx);
        hidden10_ad_x2(wl + LDS_WK(5), wl + LDS_BK(5), h, hx, ht, hxx);
        hidden10_ad_x2(wl + LDS_WK(6), wl + LDS_BK(6), h, hx, ht, hxx);
        hidden10_ad_x2(wl + LDS_WK(7), wl + LDS_BK(7), h, hx, ht, hxx);
        hidden10_ad_x2(wl + LDS_WK(8), wl + LDS_BK(8), h, hx, ht, hxx);

        // Layer 9: 10 -> 1, linear. Packed pairwise dot + horizontal add.
        float u[2], ux[2], ut[2], uxx[2];
#pragma unroll
        for (int p = 0; p < 2; ++p) {
            v2f w0 = *(const v2f*)(wl + LDS_W9);
            v2f hu, hxu, htu, hxxu;
            hu.x   = h[p][0];   hu.y   = h[p][1];
            hxu.x  = hx[p][0];  hxu.y  = hx[p][1];
            htu.x  = ht[p][0];  htu.y  = ht[p][1];
            hxxu.x = hxx[p][0]; hxxu.y = hxx[p][1];
            v2f su   = hu   * w0;
            v2f sux  = hxu  * w0;
            v2f sut  = htu  * w0;
            v2f suxx = hxxu * w0;
#pragma unroll
            for (int jp = 1; jp < 5; ++jp) {
                v2f w2 = *(const v2f*)(wl + LDS_W9 + 2 * jp);
                v2f a, b, c, d;
                a.x = h[p][2*jp];   a.y = h[p][2*jp+1];
                b.x = hx[p][2*jp];  b.y = hx[p][2*jp+1];
                c.x = ht[p][2*jp];  c.y = ht[p][2*jp+1];
                d.x = hxx[p][2*jp]; d.y = hxx[p][2*jp+1];
                su   = pk_fma(a, w2, su);
                sux  = pk_fma(b, w2, sux);
                sut  = pk_fma(c, w2, sut);
                suxx = pk_fma(d, w2, suxx);
            }
            u[p]   = wl[LDS_B9] + (su.x + su.y);
            ux[p]  = sux.x + sux.y;
            ut[p]  = sut.x + sut.y;
            uxx[p] = suxx.x + suxx.y;
        }

        float2 st;
        st.x = u[0]; st.y = u[1];
        ((float2*)out_u)[gid] = st;
        st.x = ux[0]; st.y = ux[1];
        ((float2*)out_ux)[gid] = st;
        st.x = uxx[0]; st.y = uxx[1];
        ((float2*)out_uxx)[gid] = st;
        st.x = fmaf(u[0], ux[0], ut[0]) - NU_CONST * uxx[0];
        st.y = fmaf(u[1], ux[1], ut[1]) - NU_CONST * uxx[1];
        ((float2*)out_f)[gid] = st;   // u_t + u*u_x - nu*u_xx
    } else {
        // ---------------- forward-only path: IC + boundaries ----------------
        int idx = (blockIdx.x - n_colloc_blocks) * blockDim.x + threadIdx.x;
        if (idx >= 3 * N0) return;
        const float* X;
        float* O;
        int k;
        if (idx < N0)            { X = X0; O = O0;  k = idx; }
        else if (idx < 2 * N0)   { X = XL; O = OL;  k = idx - N0; }
        else                     { X = XR; O = OR_; k = idx - 2 * N0; }

        float2 xt = ((const float2*)X)[k];
        float x = xt.x;
        float t = xt.y;

        float h[10];
#pragma unroll
        for (int j = 0; j < 10; ++j) {
            float z = fmaf(x, wl[LDS_W1 + j], fmaf(t, wl[LDS_W1 + 10 + j], wl[LDS_B1 + j]));
            h[j] = fast_tanh(z);
        }
        hidden10_fwd(wl + LDS_WK(2), wl + LDS_BK(2), h);
        hidden10_fwd(wl + LDS_WK(3), wl + LDS_BK(3), h);
        hidden10_fwd(wl + LDS_WK(4), wl + LDS_BK(4), h);
        hidden10_fwd(wl + LDS_WK(5), wl + LDS_BK(5), h);
        hidden10_fwd(wl + LDS_WK(6), wl + LDS_BK(6), h);
        hidden10_fwd(wl + LDS_WK(7), wl + LDS_BK(7), h);
        hidden10_fwd(wl + LDS_WK(8), wl + LDS_BK(8), h);

        float u = wl[LDS_B9];
#pragma unroll
        for (int i = 0; i < 10; ++i) u = fmaf(h[i], wl[LDS_W9 + i], u);
        O[k] = u;
    }
}

extern "C" void kernel_launch(void* const* d_in, const int* in_sizes, int n_in,
                              void* d_out, int out_size, void* d_ws, size_t ws_size,
                              hipStream_t stream) {
    const float* Xf = (const float*)d_in[0];
    const float* X0 = (const float*)d_in[1];
    const float* XL = (const float*)d_in[2];
    const float* XR = (const float*)d_in[3];
    const float* W[9];
    const float* B[9];
    for (int i = 0; i < 9; ++i) {
        W[i] = (const float*)d_in[4 + 2 * i];
        B[i] = (const float*)d_in[5 + 2 * i];
    }
    int NF = in_sizes[0] / 2;
    int N0 = in_sizes[1] / 2;
    int NB = in_sizes[2] / 2;
    int NF2 = NF / 2;   // pairs of points (NF = 1048576, even)

    float* out = (float*)d_out;
    float* out_u   = out;                         // u_pred_f      [NF]
    float* out_0   = out + NF;                    // u_pred_0      [N0]
    float* out_bl  = out + NF + N0;               // u_pred_b_left [NB]
    float* out_br  = out + NF + N0 + NB;          // u_pred_b_right[NB]
    float* out_f   = out + NF + N0 + 2 * NB;      // f             [NF]
    float* out_ux  = out_f + NF;                  // u_x           [NF]
    float* out_uxx = out_ux + NF;                 // u_xx          [NF]

    int n_colloc_blocks = (NF2 + 255) / 256;
    int n_fwd_blocks    = (3 * N0 + 255) / 256;
    dim3 blk(256);
    dim3 grd(n_colloc_blocks + n_fwd_blocks);
    pinn_fused_kernel<<<grd, blk, 0, stream>>>(
        Xf, X0, XL, XR,
        W[0], B[0], W[1], B[1], W[2], B[2], W[3], B[3], W[4], B[4],
        W[5], B[5], W[6], B[6], W[7], B[7], W[8], B[8],
        out_u, out_f, out_ux, out_uxx,
        out_0, out_bl, out_br,
        n_colloc_blocks, NF2, N0);
}

// Round 12
// 169.297 us; speedup vs baseline: 1.0509x; 1.0509x over previous
//
#include <hip/hip_runtime.h>
#include <math.h>

// Burgers PINN: u = MLP(x,t) (2->10x7->1, tanh), outputs u, f, u_x, u_xx at 1M
// collocation points + plain forward at 3x16384 IC/boundary points.
// Forward-mode AD with 4 channels: (val, d/dx, d/dt, d2/dx2).
//
// R12: R10 body (2 pts/thread, packed fp32, SGPR weights — best total 168.2)
// with waves_per_eu(3,4) instead of (2,2). Discriminating experiment:
// H1 (need TLP: 3 waves/SIMD -> busy >=86%, ~72 us) vs H2 (VOP3P issue-bound,
// VALUBusy undercounts -> no change, 83 us is the stream floor).

#define NU_CONST 0.0031830988618379067f   // 0.01 / pi
#define TWO_OVER_LN2 2.8853900817779268f  // 2 / ln(2)

typedef float v2f __attribute__((ext_vector_type(2)));

__device__ __forceinline__ v2f splat2(float s) {
    v2f r; r.x = s; r.y = s; return r;
}
__device__ __forceinline__ v2f pk_fma(v2f a, v2f b, v2f c) {
    return __builtin_elementwise_fma(a, b, c);
}

__device__ __forceinline__ float fast_tanh(float x) {
    float e = __builtin_amdgcn_exp2f(x * TWO_OVER_LN2);
    float r = __builtin_amdgcn_rcpf(e + 1.0f);
    return fmaf(-2.0f, r, 1.0f);
}

// Packed tanh on a pair.
__device__ __forceinline__ v2f tanh2(v2f z2) {
    v2f a2 = z2 * splat2(TWO_OVER_LN2);
    v2f e2;
    e2.x = __builtin_amdgcn_exp2f(a2.x);
    e2.y = __builtin_amdgcn_exp2f(a2.y);
    v2f ep = e2 + splat2(1.0f);
    v2f r2;
    r2.x = __builtin_amdgcn_rcpf(ep.x);
    r2.y = __builtin_amdgcn_rcpf(ep.y);
    return pk_fma(splat2(-2.0f), r2, splat2(1.0f));
}

// One hidden 10->10 tanh layer, 4 AD channels, TWO points per thread.
// Each weight pair w2 (uniform s_load) feeds 8 pk_fmas.
__device__ __forceinline__ void hidden10_ad_x2(const float* __restrict__ W,
                                               const float* __restrict__ B,
                                               float h[2][10], float hx[2][10],
                                               float ht[2][10], float hxx[2][10]) {
    v2f Z[2][5], Zx[2][5], Zt[2][5], Zxx[2][5];
#pragma unroll
    for (int jp = 0; jp < 5; ++jp) {
        v2f w2 = *(const v2f*)(W + 2 * jp);   // row 0, uniform -> s_load
        v2f b2 = *(const v2f*)(B + 2 * jp);
#pragma unroll
        for (int p = 0; p < 2; ++p) {
            Z[p][jp]   = pk_fma(splat2(h[p][0]), w2, b2);
            Zx[p][jp]  = splat2(hx[p][0]) * w2;
            Zt[p][jp]  = splat2(ht[p][0]) * w2;
            Zxx[p][jp] = splat2(hxx[p][0]) * w2;
        }
    }
#pragma unroll
    for (int i = 1; i < 10; ++i) {
#pragma unroll
        for (int jp = 0; jp < 5; ++jp) {
            v2f w2 = *(const v2f*)(W + i * 10 + 2 * jp);
#pragma unroll
            for (int p = 0; p < 2; ++p) {
                Z[p][jp]   = pk_fma(splat2(h[p][i]),   w2, Z[p][jp]);
                Zx[p][jp]  = pk_fma(splat2(hx[p][i]),  w2, Zx[p][jp]);
                Zt[p][jp]  = pk_fma(splat2(ht[p][i]),  w2, Zt[p][jp]);
                Zxx[p][jp] = pk_fma(splat2(hxx[p][i]), w2, Zxx[p][jp]);
            }
        }
    }
#pragma unroll
    for (int p = 0; p < 2; ++p) {
#pragma unroll
        for (int jp = 0; jp < 5; ++jp) {
            v2f v2v = tanh2(Z[p][jp]);
            v2f s2  = pk_fma(-v2v, v2v, splat2(1.0f));   // 1 - v^2
            v2f sx2 = s2 * Zx[p][jp];
            v2f m2v = splat2(-2.0f) * v2v;
            v2f htn2 = s2 * Zt[p][jp];
            // d2/dx2 tanh(z) = s*zxx + (-2v)*(sx*zx)
            v2f hxxn2 = pk_fma(s2, Zxx[p][jp], m2v * (sx2 * Zx[p][jp]));
            h[p][2*jp]   = v2v.x;   h[p][2*jp+1]   = v2v.y;
            hx[p][2*jp]  = sx2.x;   hx[p][2*jp+1]  = sx2.y;
            ht[p][2*jp]  = htn2.x;  ht[p][2*jp+1]  = htn2.y;
            hxx[p][2*jp] = hxxn2.x; hxx[p][2*jp+1] = hxxn2.y;
        }
    }
}

// Values-only hidden layer (boundary/IC points), packed over j-pairs.
__device__ __forceinline__ void hidden10_fwd(const float* __restrict__ W,
                                             const float* __restrict__ B,
                                             float h[10]) {
    v2f Z[5];
    {
        v2f hs = splat2(h[0]);
#pragma unroll
        for (int jp = 0; jp < 5; ++jp) {
            v2f w2 = *(const v2f*)(W + 2 * jp);
            v2f b2 = *(const v2f*)(B + 2 * jp);
            Z[jp] = pk_fma(hs, w2, b2);
        }
    }
#pragma unroll
    for (int i = 1; i < 10; ++i) {
        v2f hs = splat2(h[i]);
#pragma unroll
        for (int jp = 0; jp < 5; ++jp) {
            v2f w2 = *(const v2f*)(W + i * 10 + 2 * jp);
            Z[jp] = pk_fma(hs, w2, Z[jp]);
        }
    }
#pragma unroll
    for (int jp = 0; jp < 5; ++jp) {
        v2f v2v = tanh2(Z[jp]);
        h[2*jp] = v2v.x;
        h[2*jp+1] = v2v.y;
    }
}

__global__ __launch_bounds__(256)
__attribute__((amdgpu_waves_per_eu(3, 4)))
void pinn_fused_kernel(
    const float* __restrict__ Xf,
    const float* __restrict__ X0, const float* __restrict__ XL,
    const float* __restrict__ XR,
    const float* __restrict__ W1, const float* __restrict__ b1,
    const float* __restrict__ W2, const float* __restrict__ b2,
    const float* __restrict__ W3, const float* __restrict__ b3,
    const float* __restrict__ W4, const float* __restrict__ b4,
    const float* __restrict__ W5, const float* __restrict__ b5,
    const float* __restrict__ W6, const float* __restrict__ b6,
    const float* __restrict__ W7, const float* __restrict__ b7,
    const float* __restrict__ W8, const float* __restrict__ b8,
    const float* __restrict__ W9, const float* __restrict__ b9,
    float* __restrict__ out_u, float* __restrict__ out_f,
    float* __restrict__ out_ux, float* __restrict__ out_uxx,
    float* __restrict__ O0, float* __restrict__ OL, float* __restrict__ OR_,
    int n_colloc_blocks, int NF2, int N0) {
    if ((int)blockIdx.x < n_colloc_blocks) {
        // ------------- collocation path: 2 points, 4 AD channels -------------
        int gid = blockIdx.x * blockDim.x + threadIdx.x;   // pair index
        if (gid >= NF2) return;
        float4 xt2 = ((const float4*)Xf)[gid];   // (x0,t0,x1,t1)
        float xin[2], tin[2];
        xin[0] = xt2.x; tin[0] = xt2.y;
        xin[1] = xt2.z; tin[1] = xt2.w;

        float h[2][10], hx[2][10], ht[2][10], hxx[2][10];
        // Layer 1: 2 -> 10, tanh. Seeds: dx=(1,0), dt=(0,1), dxx=0.
#pragma unroll
        for (int jp = 0; jp < 5; ++jp) {
            v2f wx2 = *(const v2f*)(W1 + 2 * jp);        // W1 row 0
            v2f wt2 = *(const v2f*)(W1 + 10 + 2 * jp);   // W1 row 1
            v2f b2  = *(const v2f*)(b1 + 2 * jp);
#pragma unroll
            for (int p = 0; p < 2; ++p) {
                v2f z2  = pk_fma(splat2(xin[p]), wx2,
                                 pk_fma(splat2(tin[p]), wt2, b2));
                v2f v2v = tanh2(z2);
                v2f s2  = pk_fma(-v2v, v2v, splat2(1.0f));
                v2f sx2 = s2 * wx2;
                v2f m2v = splat2(-2.0f) * v2v;
                v2f st2 = s2 * wt2;
                v2f sxx2 = m2v * (sx2 * wx2);   // zxx = 0 at layer 1
                h[p][2*jp]   = v2v.x;  h[p][2*jp+1]   = v2v.y;
                hx[p][2*jp]  = sx2.x;  hx[p][2*jp+1]  = sx2.y;
                ht[p][2*jp]  = st2.x;  ht[p][2*jp+1]  = st2.y;
                hxx[p][2*jp] = sxx2.x; hxx[p][2*jp+1] = sxx2.y;
            }
        }

        hidden10_ad_x2(W2, b2, h, hx, ht, hxx);
        hidden10_ad_x2(W3, b3, h, hx, ht, hxx);
        hidden10_ad_x2(W4, b4, h, hx, ht, hxx);
        hidden10_ad_x2(W5, b5, h, hx, ht, hxx);
        hidden10_ad_x2(W6, b6, h, hx, ht, hxx);
        hidden10_ad_x2(W7, b7, h, hx, ht, hxx);
        hidden10_ad_x2(W8, b8, h, hx, ht, hxx);

        // Layer 9: 10 -> 1, linear. Packed pairwise dot + horizontal add.
        float u[2], ux[2], ut[2], uxx[2];
#pragma unroll
        for (int p = 0; p < 2; ++p) {
            v2f w0 = *(const v2f*)(W9);
            v2f hu, hxu, htu, hxxu;
            hu.x   = h[p][0];   hu.y   = h[p][1];
            hxu.x  = hx[p][0];  hxu.y  = hx[p][1];
            htu.x  = ht[p][0];  htu.y  = ht[p][1];
            hxxu.x = hxx[p][0]; hxxu.y = hxx[p][1];
            v2f su   = hu   * w0;
            v2f sux  = hxu  * w0;
            v2f sut  = htu  * w0;
            v2f suxx = hxxu * w0;
#pragma unroll
            for (int jp = 1; jp < 5; ++jp) {
                v2f w2 = *(const v2f*)(W9 + 2 * jp);
                v2f a, b, c, d;
                a.x = h[p][2*jp];   a.y = h[p][2*jp+1];
                b.x = hx[p][2*jp];  b.y = hx[p][2*jp+1];
                c.x = ht[p][2*jp];  c.y = ht[p][2*jp+1];
                d.x = hxx[p][2*jp]; d.y = hxx[p][2*jp+1];
                su   = pk_fma(a, w2, su);
                sux  = pk_fma(b, w2, sux);
                sut  = pk_fma(c, w2, sut);
                suxx = pk_fma(d, w2, suxx);
            }
            u[p]   = b9[0] + (su.x + su.y);
            ux[p]  = sux.x + sux.y;
            ut[p]  = sut.x + sut.y;
            uxx[p] = suxx.x + suxx.y;
        }

        float2 st;
        st.x = u[0]; st.y = u[1];
        ((float2*)out_u)[gid] = st;
        st.x = ux[0]; st.y = ux[1];
        ((float2*)out_ux)[gid] = st;
        st.x = uxx[0]; st.y = uxx[1];
        ((float2*)out_uxx)[gid] = st;
        st.x = fmaf(u[0], ux[0], ut[0]) - NU_CONST * uxx[0];
        st.y = fmaf(u[1], ux[1], ut[1]) - NU_CONST * uxx[1];
        ((float2*)out_f)[gid] = st;   // u_t + u*u_x - nu*u_xx
    } else {
        // ---------------- forward-only path: IC + boundaries ----------------
        int idx = (blockIdx.x - n_colloc_blocks) * blockDim.x + threadIdx.x;
        if (idx >= 3 * N0) return;
        const float* X;
        float* O;
        int k;
        if (idx < N0)            { X = X0; O = O0;  k = idx; }
        else if (idx < 2 * N0)   { X = XL; O = OL;  k = idx - N0; }
        else                     { X = XR; O = OR_; k = idx - 2 * N0; }

        float2 xt = ((const float2*)X)[k];
        float x = xt.x;
        float t = xt.y;

        float h[10];
#pragma unroll
        for (int j = 0; j < 10; ++j) {
            float z = fmaf(x, W1[j], fmaf(t, W1[10 + j], b1[j]));
            h[j] = fast_tanh(z);
        }
        hidden10_fwd(W2, b2, h);
        hidden10_fwd(W3, b3, h);
        hidden10_fwd(W4, b4, h);
        hidden10_fwd(W5, b5, h);
        hidden10_fwd(W6, b6, h);
        hidden10_fwd(W7, b7, h);
        hidden10_fwd(W8, b8, h);

        float u = b9[0];
#pragma unroll
        for (int i = 0; i < 10; ++i) u = fmaf(h[i], W9[i], u);
        O[k] = u;
    }
}

extern "C" void kernel_launch(void* const* d_in, const int* in_sizes, int n_in,
                              void* d_out, int out_size, void* d_ws, size_t ws_size,
                              hipStream_t stream) {
    const float* Xf = (const float*)d_in[0];
    const float* X0 = (const float*)d_in[1];
    const float* XL = (const float*)d_in[2];
    const float* XR = (const float*)d_in[3];
    const float* W[9];
    const float* B[9];
    for (int i = 0; i < 9; ++i) {
        W[i] = (const float*)d_in[4 + 2 * i];
        B[i] = (const float*)d_in[5 + 2 * i];
    }
    int NF = in_sizes[0] / 2;
    int N0 = in_sizes[1] / 2;
    int NB = in_sizes[2] / 2;
    int NF2 = NF / 2;   // pairs of points (NF = 1048576, even)

    float* out = (float*)d_out;
    float* out_u   = out;                         // u_pred_f      [NF]
    float* out_0   = out + NF;                    // u_pred_0      [N0]
    float* out_bl  = out + NF + N0;               // u_pred_b_left [NB]
    float* out_br  = out + NF + N0 + NB;          // u_pred_b_right[NB]
    float* out_f   = out + NF + N0 + 2 * NB;      // f             [NF]
    float* out_ux  = out_f + NF;                  // u_x           [NF]
    float* out_uxx = out_ux + NF;                 // u_xx          [NF]

    int n_colloc_blocks = (NF2 + 255) / 256;
    int n_fwd_blocks    = (3 * N0 + 255) / 256;
    dim3 blk(256);
    dim3 grd(n_colloc_blocks + n_fwd_blocks);
    pinn_fused_kernel<<<grd, blk, 0, stream>>>(
        Xf, X0, XL, XR,
        W[0], B[0], W[1], B[1], W[2], B[2], W[3], B[3], W[4], B[4],
        W[5], B[5], W[6], B[6], W[7], B[7], W[8], B[8],
        out_u, out_f, out_ux, out_uxx,
        out_0, out_bl, out_br,
        n_colloc_blocks, NF2, N0);
}